// Round 1
// baseline (722.221 us; speedup 1.0000x reference)
//
#include <hip/hip_runtime.h>

#define KNN 3
#define EPS 1e-8f
#define B_BATCH 4

// ---------------------------------------------------------------------------
// kNN: one thread per query point. Entire xyz2[b] staged in LDS (n2 <= 2048
// -> 24 KB). Candidate loop index j is wave-uniform -> LDS reads broadcast
// (no bank conflicts). Top-3 insert guarded by d < d2: once warm, all 64
// lanes fail and the branch is skipped via execz.
// ---------------------------------------------------------------------------
__global__ __launch_bounds__(256) void knn_kernel(
    const float* __restrict__ xyz1,   // (B, n1, 3) queries
    const float* __restrict__ xyz2,   // (B, n2, 3) sources
    int n1, int n2,
    int* __restrict__ out_idx,        // (B, n1, 3)
    float* __restrict__ out_w)        // (B, n1, 3) normalized weights
{
    __shared__ float s_xyz[2048 * 3];
    const int b = blockIdx.y;
    const float* src2 = xyz2 + (size_t)b * n2 * 3;
    for (int i = threadIdx.x; i < n2 * 3; i += blockDim.x)
        s_xyz[i] = src2[i];
    __syncthreads();

    const int q = blockIdx.x * blockDim.x + threadIdx.x;
    if (q >= n1) return;

    const float* p = xyz1 + ((size_t)b * n1 + q) * 3;
    const float x = p[0], y = p[1], z = p[2];

    float d0 = 1e30f, d1 = 1e30f, d2 = 1e30f;
    int   i0 = 0,     i1 = 0,     i2 = 0;

    for (int j = 0; j < n2; ++j) {
        const float dx = x - s_xyz[j * 3 + 0];
        const float dy = y - s_xyz[j * 3 + 1];
        const float dz = z - s_xyz[j * 3 + 2];
        const float d = dx * dx + dy * dy + dz * dz;
        if (d < d2) {
            if (d < d1) {
                d2 = d1; i2 = i1;
                if (d < d0) { d1 = d0; i1 = i0; d0 = d; i0 = j; }
                else        { d1 = d;  i1 = j; }
            } else {
                d2 = d; i2 = j;
            }
        }
    }

    float w0 = 1.0f / (d0 + EPS);
    float w1 = 1.0f / (d1 + EPS);
    float w2 = 1.0f / (d2 + EPS);
    const float inv = 1.0f / (w0 + w1 + w2);

    const size_t o = ((size_t)b * n1 + q) * 3;
    out_idx[o + 0] = i0; out_idx[o + 1] = i1; out_idx[o + 2] = i2;
    out_w[o + 0] = w0 * inv; out_w[o + 1] = w1 * inv; out_w[o + 2] = w2 * inv;
}

// ---------------------------------------------------------------------------
// Concat part 1: points1 (B, c1, n1) -> out channels [0, c1). Per batch this
// is a contiguous block copy of c1*n1 floats. float4 vectorized (c1*n1 is a
// multiple of 4 at every stage).
// ---------------------------------------------------------------------------
__global__ __launch_bounds__(256) void copy_kernel(
    const float4* __restrict__ src, float4* __restrict__ dst,
    int n4, int src_stride4, int dst_stride4)
{
    const int b = blockIdx.y;
    const float4* s = src + (size_t)b * src_stride4;
    float4*       d = dst + (size_t)b * dst_stride4;
    for (int i = blockIdx.x * blockDim.x + threadIdx.x; i < n4;
         i += gridDim.x * blockDim.x)
        d[i] = s[i];
}

// ---------------------------------------------------------------------------
// Interp: out[b, c_off + c, n] = sum_k w[b,n,k] * p2[b, c, idx[b,n,k]]
// Block = (channel-group of CH_TILE rows, batch). The CH_TILE rows of p2 are
// contiguous in memory -> coalesced float4 staging into LDS; each row is read
// from HBM exactly once across the whole grid. Gathers hit LDS (random 4B
// over 64 lanes ~= 2-way banking = free). Stores coalesced along n.
// ---------------------------------------------------------------------------
template <int CH_TILE>
__global__ __launch_bounds__(256) void interp_kernel(
    const float* __restrict__ p2,       // (B, c2, n2)
    const int* __restrict__ knn_idx,    // (B, n1, 3)
    const float* __restrict__ knn_w,    // (B, n1, 3)
    float* __restrict__ out,            // (B, c_out, n1)
    int n1, int n2, int c2, int c_out, int c_off)
{
    extern __shared__ float s_rows[];   // CH_TILE * n2 floats
    const int b  = blockIdx.y;
    const int c0 = blockIdx.x * CH_TILE;

    const float4* src4 = (const float4*)(p2 + ((size_t)b * c2 + c0) * n2);
    float4* s4 = (float4*)s_rows;
    const int total4 = CH_TILE * n2 / 4;
    for (int i = threadIdx.x; i < total4; i += blockDim.x)
        s4[i] = src4[i];
    __syncthreads();

    const int*   kid = knn_idx + (size_t)b * n1 * KNN;
    const float* kw  = knn_w  + (size_t)b * n1 * KNN;
    float* outb = out + ((size_t)b * c_out + c_off + c0) * n1;

    for (int q = threadIdx.x; q < n1; q += blockDim.x) {
        const int   j0 = kid[q * 3 + 0], j1 = kid[q * 3 + 1], j2 = kid[q * 3 + 2];
        const float w0 = kw[q * 3 + 0],  w1 = kw[q * 3 + 1],  w2 = kw[q * 3 + 2];
#pragma unroll
        for (int c = 0; c < CH_TILE; ++c) {
            const float* row = s_rows + c * n2;
            const float v = w0 * row[j0] + w1 * row[j1] + w2 * row[j2];
            outb[(size_t)c * n1 + q] = v;
        }
    }
}

// ---------------------------------------------------------------------------
extern "C" void kernel_launch(void* const* d_in, const int* in_sizes, int n_in,
                              void* d_out, int out_size, void* d_ws, size_t ws_size,
                              hipStream_t stream)
{
    // setup_inputs order: xyz0, x0, xyz1, x1, xyz2, x2, xyz3, x3, xyz4, x4
    const float* xyz[5];
    const float* xf[5];
    for (int i = 0; i < 5; ++i) {
        xyz[i] = (const float*)d_in[2 * i];
        xf[i]  = (const float*)d_in[2 * i + 1];
    }

    // Workspace layout (floats):
    //   interm0: (4, 1536, 128)  =   786432
    //   interm1: (4, 1792, 512)  =  3670016
    //   interm2: (4, 1920, 2048) = 15728640
    //   knn_w  : (4, 8192, 3)    =    98304
    //   knn_idx: (4, 8192, 3)    =    98304
    float* ws = (float*)d_ws;
    float* interm0 = ws;
    float* interm1 = interm0 + (size_t)4 * 1536 * 128;
    float* interm2 = interm1 + (size_t)4 * 1792 * 512;
    float* knn_w   = interm2 + (size_t)4 * 1920 * 2048;
    int*   knn_idx = (int*)(knn_w + (size_t)4 * 8192 * 3);

    struct Stage {
        const float* xq;   // query coords  (B, n1, 3)
        const float* xs;   // source coords (B, n2, 3)
        const float* p1;   // skip features (B, c1, n1)
        const float* p2;   // deep features (B, c2, n2)
        int n1, n2, c1, c2;
        float* out;        // (B, c1+c2, n1)
    };

    const Stage st[4] = {
        { xyz[3], xyz[4], xf[3], xf[4],   128,   32, 512, 1024, interm0 },
        { xyz[2], xyz[3], xf[2], interm0, 512,  128, 256, 1536, interm1 },
        { xyz[1], xyz[2], xf[1], interm1, 2048, 512, 128, 1792, interm2 },
        { xyz[0], xyz[1], xf[0], interm2, 8192, 2048, 64, 1920, (float*)d_out },
    };

    constexpr int CH_TILE = 4;

    for (int s = 0; s < 4; ++s) {
        const Stage& S = st[s];
        const int c_out = S.c1 + S.c2;

        // 1) kNN
        {
            dim3 grid((S.n1 + 255) / 256, B_BATCH);
            knn_kernel<<<grid, 256, 0, stream>>>(S.xq, S.xs, S.n1, S.n2,
                                                 knn_idx, knn_w);
        }
        // 2) copy skip features into channels [0, c1)
        {
            const int n4 = S.c1 * S.n1 / 4;
            int blocks = (n4 + 255) / 256;
            if (blocks > 2048) blocks = 2048;
            dim3 grid(blocks, B_BATCH);
            copy_kernel<<<grid, 256, 0, stream>>>(
                (const float4*)S.p1, (float4*)S.out,
                n4, S.c1 * S.n1 / 4, c_out * S.n1 / 4);
        }
        // 3) interpolate into channels [c1, c1+c2)
        {
            dim3 grid(S.c2 / CH_TILE, B_BATCH);
            const size_t lds = (size_t)CH_TILE * S.n2 * sizeof(float);
            interp_kernel<CH_TILE><<<grid, 256, lds, stream>>>(
                S.p2, knn_idx, knn_w, S.out,
                S.n1, S.n2, S.c2, c_out, S.c1);
        }
    }
}

// Round 2
// 451.184 us; speedup vs baseline: 1.6007x; 1.6007x over previous
//
#include <hip/hip_runtime.h>

#define KNN 3
#define EPS 1e-8f
#define B_BATCH 4
#define QPB 16   // queries per block = 4 waves x 4 queries/wave

// ---------------------------------------------------------------------------
// kNN, wave-per-query version.
//
// Block = 256 threads (4 waves); each block handles QPB=16 queries, staging
// the whole xyz2[b] in LDS as SoA (stride-1 across lanes -> 2-way bank
// aliasing = free). Each of the 64 lanes scans n2/64 candidates keeping a
// sorted top-3 of packed u64 keys (dist_bits<<32 | idx); dist >= 0 so float
// bit order == value order, and the low-word index tie-breaks to the smaller
// j like jax top_k. Branchless insert = 3 min + 3 max (u64). A 6-step
// __shfl_xor butterfly merges the 64 lane-local top-3 sets; every lane ends
// with the global top-3 (symmetric merge), lane 0 writes idx + normalized
// inverse-distance weights.
// ---------------------------------------------------------------------------
__device__ __forceinline__ unsigned long long u64min(unsigned long long a,
                                                     unsigned long long b) {
    return a < b ? a : b;
}
__device__ __forceinline__ unsigned long long u64max(unsigned long long a,
                                                     unsigned long long b) {
    return a > b ? a : b;
}

__global__ __launch_bounds__(256) void knn_kernel(
    const float* __restrict__ xyz1,   // (B, n1, 3) queries
    const float* __restrict__ xyz2,   // (B, n2, 3) sources
    int n1, int n2,
    int* __restrict__ out_idx,        // (B, n1, 3)
    float* __restrict__ out_w)        // (B, n1, 3) normalized weights
{
    __shared__ float s_x[2048], s_y[2048], s_z[2048];
    const int b = blockIdx.y;
    const float* src2 = xyz2 + (size_t)b * n2 * 3;
    for (int i = threadIdx.x; i < n2; i += blockDim.x) {
        s_x[i] = src2[i * 3 + 0];
        s_y[i] = src2[i * 3 + 1];
        s_z[i] = src2[i * 3 + 2];
    }
    __syncthreads();

    const int lane = threadIdx.x & 63;
    const int wave = threadIdx.x >> 6;
    const int q0 = blockIdx.x * QPB + wave * (QPB / 4);

    for (int r = 0; r < QPB / 4; ++r) {
        const int q = q0 + r;
        const float* p = xyz1 + ((size_t)b * n1 + q) * 3;
        const float x = p[0], y = p[1], z = p[2];

        unsigned long long k0 = ~0ull, k1 = ~0ull, k2 = ~0ull;

        for (int j = lane; j < n2; j += 64) {
            const float dx = x - s_x[j];
            const float dy = y - s_y[j];
            const float dz = z - s_z[j];
            const float d = fmaf(dz, dz, fmaf(dy, dy, dx * dx));
            const unsigned long long key =
                ((unsigned long long)__float_as_uint(d) << 32) | (unsigned)j;
            const unsigned long long u = u64max(key, k0);
            k0 = u64min(key, k0);
            const unsigned long long v = u64max(u, k1);
            k1 = u64min(u, k1);
            k2 = u64min(v, k2);
        }

        // butterfly merge across the wave: both partners compute the same
        // merged top-3, so after 6 steps all lanes agree.
#pragma unroll
        for (int m = 1; m < 64; m <<= 1) {
            unsigned long long b0 = __shfl_xor(k0, m, 64);
            unsigned long long b1 = __shfl_xor(k1, m, 64);
            unsigned long long b2 = __shfl_xor(k2, m, 64);
            unsigned long long u, v;
            u = u64max(b0, k0); k0 = u64min(b0, k0);
            v = u64max(u, k1);  k1 = u64min(u, k1);
            k2 = u64min(v, k2);
            u = u64max(b1, k0); k0 = u64min(b1, k0);
            v = u64max(u, k1);  k1 = u64min(u, k1);
            k2 = u64min(v, k2);
            u = u64max(b2, k0); k0 = u64min(b2, k0);
            v = u64max(u, k1);  k1 = u64min(u, k1);
            k2 = u64min(v, k2);
        }

        if (lane == 0) {
            const float d0 = __uint_as_float((unsigned)(k0 >> 32));
            const float d1 = __uint_as_float((unsigned)(k1 >> 32));
            const float d2 = __uint_as_float((unsigned)(k2 >> 32));
            float w0 = 1.0f / (d0 + EPS);
            float w1 = 1.0f / (d1 + EPS);
            float w2 = 1.0f / (d2 + EPS);
            const float inv = 1.0f / (w0 + w1 + w2);
            const size_t o = ((size_t)b * n1 + q) * 3;
            out_idx[o + 0] = (int)(unsigned)(k0 & 0xFFFFFFFFu);
            out_idx[o + 1] = (int)(unsigned)(k1 & 0xFFFFFFFFu);
            out_idx[o + 2] = (int)(unsigned)(k2 & 0xFFFFFFFFu);
            out_w[o + 0] = w0 * inv;
            out_w[o + 1] = w1 * inv;
            out_w[o + 2] = w2 * inv;
        }
    }
}

// ---------------------------------------------------------------------------
// Concat part 1: points1 (B, c1, n1) -> out channels [0, c1). Contiguous
// per-batch block copy, float4 vectorized.
// ---------------------------------------------------------------------------
__global__ __launch_bounds__(256) void copy_kernel(
    const float4* __restrict__ src, float4* __restrict__ dst,
    int n4, int src_stride4, int dst_stride4)
{
    const int b = blockIdx.y;
    const float4* s = src + (size_t)b * src_stride4;
    float4*       d = dst + (size_t)b * dst_stride4;
    for (int i = blockIdx.x * blockDim.x + threadIdx.x; i < n4;
         i += gridDim.x * blockDim.x)
        d[i] = s[i];
}

// ---------------------------------------------------------------------------
// Interp: out[b, c_off + c, n] = sum_k w[b,n,k] * p2[b, c, idx[b,n,k]]
// CH_TILE contiguous channel rows of p2 staged in LDS (coalesced float4),
// each row read from HBM exactly once; gathers hit LDS; stores coalesced.
// ---------------------------------------------------------------------------
template <int CH_TILE>
__global__ __launch_bounds__(256) void interp_kernel(
    const float* __restrict__ p2,       // (B, c2, n2)
    const int* __restrict__ knn_idx,    // (B, n1, 3)
    const float* __restrict__ knn_w,    // (B, n1, 3)
    float* __restrict__ out,            // (B, c_out, n1)
    int n1, int n2, int c2, int c_out, int c_off)
{
    extern __shared__ float s_rows[];   // CH_TILE * n2 floats
    const int b  = blockIdx.y;
    const int c0 = blockIdx.x * CH_TILE;

    const float4* src4 = (const float4*)(p2 + ((size_t)b * c2 + c0) * n2);
    float4* s4 = (float4*)s_rows;
    const int total4 = CH_TILE * n2 / 4;
    for (int i = threadIdx.x; i < total4; i += blockDim.x)
        s4[i] = src4[i];
    __syncthreads();

    const int*   kid = knn_idx + (size_t)b * n1 * KNN;
    const float* kw  = knn_w  + (size_t)b * n1 * KNN;
    float* outb = out + ((size_t)b * c_out + c_off + c0) * n1;

    for (int q = threadIdx.x; q < n1; q += blockDim.x) {
        const int   j0 = kid[q * 3 + 0], j1 = kid[q * 3 + 1], j2 = kid[q * 3 + 2];
        const float w0 = kw[q * 3 + 0],  w1 = kw[q * 3 + 1],  w2 = kw[q * 3 + 2];
#pragma unroll
        for (int c = 0; c < CH_TILE; ++c) {
            const float* row = s_rows + c * n2;
            const float v = w0 * row[j0] + w1 * row[j1] + w2 * row[j2];
            outb[(size_t)c * n1 + q] = v;
        }
    }
}

// ---------------------------------------------------------------------------
extern "C" void kernel_launch(void* const* d_in, const int* in_sizes, int n_in,
                              void* d_out, int out_size, void* d_ws, size_t ws_size,
                              hipStream_t stream)
{
    // setup_inputs order: xyz0, x0, xyz1, x1, xyz2, x2, xyz3, x3, xyz4, x4
    const float* xyz[5];
    const float* xf[5];
    for (int i = 0; i < 5; ++i) {
        xyz[i] = (const float*)d_in[2 * i];
        xf[i]  = (const float*)d_in[2 * i + 1];
    }

    float* ws = (float*)d_ws;
    float* interm0 = ws;                                   // (4,1536,128)
    float* interm1 = interm0 + (size_t)4 * 1536 * 128;     // (4,1792,512)
    float* interm2 = interm1 + (size_t)4 * 1792 * 512;     // (4,1920,2048)
    float* knn_w   = interm2 + (size_t)4 * 1920 * 2048;    // (4,8192,3)
    int*   knn_idx = (int*)(knn_w + (size_t)4 * 8192 * 3); // (4,8192,3)

    struct Stage {
        const float* xq;   // query coords  (B, n1, 3)
        const float* xs;   // source coords (B, n2, 3)
        const float* p1;   // skip features (B, c1, n1)
        const float* p2;   // deep features (B, c2, n2)
        int n1, n2, c1, c2;
        float* out;        // (B, c1+c2, n1)
    };

    const Stage st[4] = {
        { xyz[3], xyz[4], xf[3], xf[4],   128,   32, 512, 1024, interm0 },
        { xyz[2], xyz[3], xf[2], interm0, 512,  128, 256, 1536, interm1 },
        { xyz[1], xyz[2], xf[1], interm1, 2048, 512, 128, 1792, interm2 },
        { xyz[0], xyz[1], xf[0], interm2, 8192, 2048, 64, 1920, (float*)d_out },
    };

    constexpr int CH_TILE = 4;

    for (int s = 0; s < 4; ++s) {
        const Stage& S = st[s];
        const int c_out = S.c1 + S.c2;

        // 1) kNN (wave-per-query; n1 divisible by QPB=16 at every stage)
        {
            dim3 grid(S.n1 / QPB, B_BATCH);
            knn_kernel<<<grid, 256, 0, stream>>>(S.xq, S.xs, S.n1, S.n2,
                                                 knn_idx, knn_w);
        }
        // 2) copy skip features into channels [0, c1)
        {
            const int n4 = S.c1 * S.n1 / 4;
            int blocks = (n4 + 255) / 256;
            if (blocks > 2048) blocks = 2048;
            dim3 grid(blocks, B_BATCH);
            copy_kernel<<<grid, 256, 0, stream>>>(
                (const float4*)S.p1, (float4*)S.out,
                n4, S.c1 * S.n1 / 4, c_out * S.n1 / 4);
        }
        // 3) interpolate into channels [c1, c1+c2)
        {
            dim3 grid(S.c2 / CH_TILE, B_BATCH);
            const size_t lds = (size_t)CH_TILE * S.n2 * sizeof(float);
            interp_kernel<CH_TILE><<<grid, 256, lds, stream>>>(
                S.p2, knn_idx, knn_w, S.out,
                S.n1, S.n2, S.c2, c_out, S.c1);
        }
    }
}